// Round 13
// baseline (48.900 us; speedup 1.0000x reference)
//
#include <hip/hip_runtime.h>
#include <cmath>

namespace {

typedef _Float16 h8 __attribute__((ext_vector_type(8)));

constexpr int C_     = 64;
constexpr int L_     = 32768;
constexpr int TILE   = 4096;
constexpr int HALO   = 776;           // receptive field 765, rounded to unit-8
constexpr int NB     = TILE + HALO;   // 4872 halfs
constexpr int NU     = NB / 8;        // 609 h8 units
constexpr int HALO_U = HALO / 8;      // 97
constexpr int NT     = L_ / TILE;     // 8 tiles per row
constexpr int BLK    = 256;
constexpr int S2N    = NU - 2 * BLK;  // 97: threads owning a third unit

__device__ __forceinline__ h8 ld8(const _Float16* p) { return *reinterpret_cast<const h8*>(p); }
__device__ __forceinline__ void st8(_Float16* p, h8 v) { *reinterpret_cast<h8*>(p) = v; }
__device__ __forceinline__ float4 ld4f(const float* p) { return *reinterpret_cast<const float4*>(p); }
__device__ __forceinline__ void st4f(float* p, float4 v) { *reinterpret_cast<float4*>(p) = v; }
__device__ __forceinline__ h8 sp8(_Float16 v) { return (h8){v,v,v,v,v,v,v,v}; }

// Guaranteed v_pk_fma_f16 (r10: +5% vs mul/add trees).
__device__ __forceinline__ h8 fma8(h8 a, h8 b, h8 c) {
    return __builtin_elementwise_fma(a, b, c);
}

template<int K>
__device__ __forceinline__ h8 shconc(h8 A, h8 B) {
    return __builtin_shufflevector(A, B, K, K+1, K+2, K+3, K+4, K+5, K+6, K+7);
}

// tanh-form GELU: v * sigmoid(1.5958*v + 0.07135*v^3); absmax-verified vs erf
// across seven rounds (identical 0.0078125 overall absmax).
__device__ __forceinline__ float gelu_f(float v) {
    const float z = v * (1.5957691216057308f + 0.0713548162726f * v * v);
    const float e = __expf(-z);
    return v * __builtin_amdgcn_rcpf(1.0f + e);
}

// Two 4-tap dot products (y-accumulate + new-low) from assembled taps.
template<bool LAST>
__device__ __forceinline__ void dot4(const h8 T0, const h8 T1, const h8 T2,
                                     h8& lwv, h8& yv, bool doY,
                                     const _Float16* c1, const _Float16* c0)
{
    const h8 T3 = lwv;
    if (doY) {
        h8 yt = yv;
        yt = fma8(sp8(c1[0]), T0, yt);
        yt = fma8(sp8(c1[1]), T1, yt);
        yt = fma8(sp8(c1[2]), T2, yt);
        yt = fma8(sp8(c1[3]), T3, yt);
        yv = yt;
    }
    h8 nl = sp8(c0[0]) * T0;
    nl = fma8(sp8(c0[1]), T1, nl);
    nl = fma8(sp8(c0[2]), T2, nl);
    nl = fma8(sp8(c0[3]), T3, nl);
    if constexpr (LAST) yv += nl;      // c0 pre-folded with w0
    else lwv = nl;
}

// One level, dilation D. LOAD PHASE: all slots' LDS reads issued first with
// CLAMPED addresses (inactive threads read the frontier unit's taps — always
// in-bounds by the frontier property: 8*STARTU-3D >= 0 for every level).
// COMPUTE PHASE: guarded per slot (guards bound live ranges; r4-r7 showed
// fully-unguarded variants balloon to 188 VGPR or scratch-demote).
// Frontier recursion (correctness-proven r3..r12): STARTU per level
// 1,2,4,7,13,25,49,97; valid unit g at level D reads down to g-3D/8 >= prev
// STARTU, so below-frontier garbage is never read.
template<int D, int STARTU, bool LAST>
__device__ __forceinline__ void level_pass(const _Float16* __restrict__ src,
                                           _Float16* __restrict__ dst,
                                           const float* h0f, const float* h1f,
                                           float wi, float w0,
                                           h8* lw, h8* yacc, int tid)
{
    _Float16 c1[4], c0[4];
#pragma unroll
    for (int t = 0; t < 4; ++t) {
        c1[t] = (_Float16)(wi * h1f[t]);
        c0[t] = (_Float16)(LAST ? w0 * h0f[t] : h0f[t]);
    }

    const bool act0 = (tid >= STARTU);
    const bool act2 = (tid < S2N);
    const bool y0   = (tid >= HALO_U);
    const int  g0   = act0 ? tid : STARTU;            // clamped slot-0 unit
    const int  g1   = tid + BLK;                      // always active
    const int  g2   = act2 ? (tid + 2 * BLK) : (NU - 1);  // clamped slot-2 unit

    if constexpr (D >= 8) {
        // ---- load phase: 9 ds_read_b128, no dependent math between them ----
        const h8 A0 = ld8(&src[8 * g0 - 3 * D]);
        const h8 A1 = ld8(&src[8 * g0 - 2 * D]);
        const h8 A2 = ld8(&src[8 * g0 - D]);
        const h8 B0 = ld8(&src[8 * g1 - 3 * D]);
        const h8 B1 = ld8(&src[8 * g1 - 2 * D]);
        const h8 B2 = ld8(&src[8 * g1 - D]);
        const h8 C0 = ld8(&src[8 * g2 - 3 * D]);
        const h8 C1 = ld8(&src[8 * g2 - 2 * D]);
        const h8 C2 = ld8(&src[8 * g2 - D]);
        // ---- compute phase (guarded) ----
        if (act0) {
            dot4<LAST>(A0, A1, A2, lw[0], yacc[0], y0, c1, c0);
            if constexpr (!LAST) st8(&dst[8 * tid], lw[0]);
        }
        {
            dot4<LAST>(B0, B1, B2, lw[1], yacc[1], true, c1, c0);
            if constexpr (!LAST) st8(&dst[8 * g1], lw[1]);
        }
        if (act2) {
            dot4<LAST>(C0, C1, C2, lw[2], yacc[2], true, c1, c0);
            if constexpr (!LAST) st8(&dst[8 * (tid + 2 * BLK)], lw[2]);
        }
    } else {
        // ---- load phase: left-neighbor unit(s) per slot ----
        const h8 La = ld8(&src[8 * (g0 - 1)]);        // g0 >= STARTU >= 1
        const h8 Lb = ld8(&src[8 * (g1 - 1)]);
        const h8 Lc = ld8(&src[8 * (g2 - 1)]);
        h8 LLa, LLb, LLc;
        if constexpr (D == 4) {                        // needs unit g-2 too
            LLa = ld8(&src[8 * (g0 - 2)]);             // STARTU=4 -> g0-2 >= 2
            LLb = ld8(&src[8 * (g1 - 2)]);
            LLc = ld8(&src[8 * (g2 - 2)]);
        }
        // ---- compute phase (guarded) ----
        auto taps_and_dot = [&](const h8 Lv, const h8 LL, h8& lwv, h8& yv, bool doY) {
            const h8 T3 = lwv;
            h8 T0, T1, T2;
            if constexpr (D == 1) {
                T0 = shconc<5>(Lv, T3); T1 = shconc<6>(Lv, T3); T2 = shconc<7>(Lv, T3);
            } else if constexpr (D == 2) {
                T0 = shconc<2>(Lv, T3); T1 = shconc<4>(Lv, T3); T2 = shconc<6>(Lv, T3);
            } else {  // D == 4
                T0 = shconc<4>(LL, Lv); T1 = Lv; T2 = shconc<4>(Lv, T3);
            }
            dot4<LAST>(T0, T1, T2, lwv, yv, doY, c1, c0);
        };
        if (act0) {
            taps_and_dot(La, (D == 4) ? LLa : La, lw[0], yacc[0], y0);
            if constexpr (!LAST) st8(&dst[8 * tid], lw[0]);
        }
        {
            taps_and_dot(Lb, (D == 4) ? LLb : Lb, lw[1], yacc[1], true);
            if constexpr (!LAST) st8(&dst[8 * g1], lw[1]);
        }
        if (act2) {
            taps_and_dot(Lc, (D == 4) ? LLc : Lc, lw[2], yacc[2], true);
            if constexpr (!LAST) st8(&dst[8 * (tid + 2 * BLK)], lw[2]);
        }
    }
}

// min-waves=5 (VGPR cap 102): the load-hoisted level needs ~60-90 live VGPR
// (9 h8 taps in flight + 6 h8 accumulators). Caps BELOW pressure caused
// catastrophic scratch demotion (r4-r7) — 102 leaves margin. LDS 19968B
// still allows 8 blocks/CU; VGPR will set the resident-wave count.
__global__ __launch_bounds__(BLK, 5)
void cmrc_kernel(const float* __restrict__ x,
                 const float* __restrict__ h0,
                 const float* __restrict__ h1,
                 const float* __restrict__ w,
                 float* __restrict__ out)
{
    __shared__ alignas(16) _Float16 buf[2][NB];

    const int tid  = threadIdx.x;
    const int blk  = blockIdx.x;
    const int tile = blk % NT;
    const int bc   = blk / NT;            // b*C + c
    const int c    = bc % C_;
    const long row = (long)bc * L_;
    const int  t0  = tile * TILE - HALO;  // global pos of buffer p=0

    float h0v[4], h1v[4];
#pragma unroll
    for (int k = 0; k < 4; ++k) { h0v[k] = h0[c*4+k]; h1v[k] = h1[c*4+k]; }
    float wv[10];
#pragma unroll
    for (int i = 0; i < 10; ++i) wv[i] = w[c*10+i];

    h8 lw[3];     // running low residual (own units, registers)
    h8 yacc[3];   // packed y accumulator

    const _Float16 w9h = (_Float16)wv[9];

    // Stage x as fp16 (zeros left of t=0); init lw = x, y = w9*x.
#pragma unroll
    for (int u = 0; u < 3; ++u) {
        yacc[u] = sp8((_Float16)0.f);
        const int un = tid + u * BLK;
        if (un < NU) {
            const int p = 8 * un;
            const int t = t0 + p;
            float4 xa = make_float4(0.f, 0.f, 0.f, 0.f);
            float4 xb = make_float4(0.f, 0.f, 0.f, 0.f);
            if (t >= 0) { xa = ld4f(&x[row + t]); xb = ld4f(&x[row + t + 4]); }
            h8 hv;
            hv[0] = (_Float16)xa.x; hv[1] = (_Float16)xa.y;
            hv[2] = (_Float16)xa.z; hv[3] = (_Float16)xa.w;
            hv[4] = (_Float16)xb.x; hv[5] = (_Float16)xb.y;
            hv[6] = (_Float16)xb.z; hv[7] = (_Float16)xb.w;
            st8(&buf[0][p], hv);
            lw[u] = hv;
            if (un >= HALO_U) yacc[u] = sp8(w9h) * hv;
        }
    }
    __syncthreads();

    level_pass<1,   1,  false>(buf[0], buf[1], h0v, h1v, wv[8], 0.f, lw, yacc, tid); __syncthreads();
    level_pass<2,   2,  false>(buf[1], buf[0], h0v, h1v, wv[7], 0.f, lw, yacc, tid); __syncthreads();
    level_pass<4,   4,  false>(buf[0], buf[1], h0v, h1v, wv[6], 0.f, lw, yacc, tid); __syncthreads();
    level_pass<8,   7,  false>(buf[1], buf[0], h0v, h1v, wv[5], 0.f, lw, yacc, tid); __syncthreads();
    level_pass<16,  13, false>(buf[0], buf[1], h0v, h1v, wv[4], 0.f, lw, yacc, tid); __syncthreads();
    level_pass<32,  25, false>(buf[1], buf[0], h0v, h1v, wv[3], 0.f, lw, yacc, tid); __syncthreads();
    level_pass<64,  49, false>(buf[0], buf[1], h0v, h1v, wv[2], 0.f, lw, yacc, tid); __syncthreads();
    level_pass<128, 97, true >(buf[1], buf[0], h0v, h1v, wv[1], wv[0], lw, yacc, tid);

    // Epilogue: unpack to fp32, GELU, two float4 stores per unit.
#pragma unroll
    for (int u = 0; u < 3; ++u) {
        const int un = tid + u * BLK;
        if (un >= HALO_U && un < NU) {
            const int p = 8 * un;
            const h8 v = yacc[u];
            float4 oa, ob;
            oa.x = gelu_f((float)v[0]); oa.y = gelu_f((float)v[1]);
            oa.z = gelu_f((float)v[2]); oa.w = gelu_f((float)v[3]);
            ob.x = gelu_f((float)v[4]); ob.y = gelu_f((float)v[5]);
            ob.z = gelu_f((float)v[6]); ob.w = gelu_f((float)v[7]);
            st4f(&out[row + t0 + p], oa);
            st4f(&out[row + t0 + p + 4], ob);
        }
    }
}

}  // namespace

extern "C" void kernel_launch(void* const* d_in, const int* in_sizes, int n_in,
                              void* d_out, int out_size, void* d_ws, size_t ws_size,
                              hipStream_t stream)
{
    const float* x  = (const float*)d_in[0];
    const float* h0 = (const float*)d_in[1];
    const float* h1 = (const float*)d_in[2];
    const float* w  = (const float*)d_in[3];
    float* out = (float*)d_out;

    const int nblocks = (out_size / L_) * NT;   // B*C*NT = 4096
    cmrc_kernel<<<nblocks, BLK, 0, stream>>>(x, h0, h1, w, out);
}

// Round 14
// 46.912 us; speedup vs baseline: 1.0424x; 1.0424x over previous
//
#include <hip/hip_runtime.h>
#include <cmath>

namespace {

typedef _Float16 h8 __attribute__((ext_vector_type(8)));
typedef _Float16 h2 __attribute__((ext_vector_type(2)));
typedef __fp16   fp2 __attribute__((ext_vector_type(2)));   // cvt_pkrtz native type

constexpr int C_     = 64;
constexpr int L_     = 32768;
constexpr int TILE   = 2048;
constexpr int HALO   = 776;           // receptive field 765, rounded to unit-8
constexpr int NB     = TILE + HALO;   // 2824 halfs
constexpr int NU     = NB / 8;        // 353 h8 units
constexpr int HALO_U = HALO / 8;      // 97
constexpr int NT     = L_ / TILE;     // 16 tiles per row
constexpr int BLK    = 128;           // 2-wave blocks: 13-14 independent
                                      // barrier domains per CU (r14 theory)
constexpr int UMAX   = (NU + BLK - 1) / BLK;   // 3 unit-slots per thread

__device__ __forceinline__ h8 ld8(const _Float16* p) { return *reinterpret_cast<const h8*>(p); }
__device__ __forceinline__ void st8(_Float16* p, h8 v) { *reinterpret_cast<h8*>(p) = v; }
__device__ __forceinline__ float4 ld4f(const float* p) { return *reinterpret_cast<const float4*>(p); }
__device__ __forceinline__ void st4f(float* p, float4 v) { *reinterpret_cast<float4*>(p) = v; }
__device__ __forceinline__ h8 sp8(_Float16 v) { return (h8){v,v,v,v,v,v,v,v}; }

// Guaranteed v_pk_fma_f16 (r10: +5% vs mul/add trees).
__device__ __forceinline__ h8 fma8(h8 a, h8 b, h8 c) {
    return __builtin_elementwise_fma(a, b, c);
}

template<int K>
__device__ __forceinline__ h8 shconc(h8 A, h8 B) {
    return __builtin_shufflevector(A, B, K, K+1, K+2, K+3, K+4, K+5, K+6, K+7);
}

// f32x8 -> fp16x8 via v_cvt_pkrtz_f16_f32 (1 instr / 2 elems).
__device__ __forceinline__ h2 pkrtz(float lo, float hi) {
    const fp2 r = __builtin_amdgcn_cvt_pkrtz(lo, hi);
    return __builtin_bit_cast(h2, r);
}
__device__ __forceinline__ h8 pack8(float4 a, float4 b) {
    const h2 p0 = pkrtz(a.x, a.y);
    const h2 p1 = pkrtz(a.z, a.w);
    const h2 p2 = pkrtz(b.x, b.y);
    const h2 p3 = pkrtz(b.z, b.w);
    return (h8){p0[0], p0[1], p1[0], p1[1], p2[0], p2[1], p3[0], p3[1]};
}

// tanh-form GELU: v * sigmoid(1.5958*v + 0.07135*v^3); absmax-verified vs erf
// across eight rounds (identical 0.0078125 overall absmax).
__device__ __forceinline__ float gelu_f(float v) {
    const float z = v * (1.5957691216057308f + 0.0713548162726f * v * v);
    const float e = __expf(-z);
    return v * __builtin_amdgcn_rcpf(1.0f + e);
}

// One level, dilation D. T3 = own unit (registers); T0..T2 from LDS.
// Frontier recursion (correctness-proven r3..r13): STARTU per level
// 1,2,4,7,13,25,49,97; valid unit g at level D reads down to g-3D/8 >= prev
// STARTU, so below-frontier garbage is never read. Guards kept per-slot: they
// bound live ranges (r4-r7: unguarded variants -> 188 VGPR or demotion).
template<int D, int STARTU, bool LAST>
__device__ __forceinline__ void level_pass(const _Float16* __restrict__ src,
                                           _Float16* __restrict__ dst,
                                           const float* h0f, const float* h1f,
                                           float wi, float w0,
                                           h8* lw, h8* yacc, int tid)
{
    _Float16 c1[4], c0[4];
#pragma unroll
    for (int t = 0; t < 4; ++t) {
        c1[t] = (_Float16)(wi * h1f[t]);
        c0[t] = (_Float16)(LAST ? w0 * h0f[t] : h0f[t]);
    }

#pragma unroll
    for (int u = 0; u < UMAX; ++u) {
        const int un = tid + u * BLK;
        if (un >= STARTU && un < NU) {
            const int p = 8 * un;
            const h8 T3 = lw[u];
            h8 T0, T1, T2;
            if constexpr (D == 1) {
                h8 Lv = ld8(&src[p - 8]);
                T0 = shconc<5>(Lv, T3);
                T1 = shconc<6>(Lv, T3);
                T2 = shconc<7>(Lv, T3);
            } else if constexpr (D == 2) {
                h8 Lv = ld8(&src[p - 8]);
                T0 = shconc<2>(Lv, T3);
                T1 = shconc<4>(Lv, T3);
                T2 = shconc<6>(Lv, T3);
            } else if constexpr (D == 4) {
                h8 Lv  = ld8(&src[p - 8]);
                h8 LL  = ld8(&src[p - 16]);
                T0 = shconc<4>(LL, Lv);
                T1 = Lv;
                T2 = shconc<4>(Lv, T3);
            } else {
                T0 = ld8(&src[p - 3 * D]);
                T1 = ld8(&src[p - 2 * D]);
                T2 = ld8(&src[p - D]);
            }
            if (un >= HALO_U) {   // y only matters inside the output tile
                h8 yv = yacc[u];
                yv = fma8(sp8(c1[0]), T0, yv);
                yv = fma8(sp8(c1[1]), T1, yv);
                yv = fma8(sp8(c1[2]), T2, yv);
                yv = fma8(sp8(c1[3]), T3, yv);
                yacc[u] = yv;
            }
            h8 nl = sp8(c0[0]) * T0;
            nl = fma8(sp8(c0[1]), T1, nl);
            nl = fma8(sp8(c0[2]), T2, nl);
            nl = fma8(sp8(c0[3]), T3, nl);
            if constexpr (LAST) {
                yacc[u] += nl;          // c0 already folded with w0
            } else {
                lw[u] = nl;
                st8(&dst[p], nl);
            }
        }
    }
}

// (128,8): VGPR cap 64 — this guarded structure measured 24 VGPR (r10), 2.6x
// headroom. LDS 2x5648B -> 13-14 blocks/CU (LDS-limited), each an independent
// 2-wave barrier domain.
__global__ __launch_bounds__(BLK, 8)
void cmrc_kernel(const float* __restrict__ x,
                 const float* __restrict__ h0,
                 const float* __restrict__ h1,
                 const float* __restrict__ w,
                 float* __restrict__ out)
{
    __shared__ alignas(16) _Float16 buf[2][NB];

    const int tid  = threadIdx.x;
    const int blk  = blockIdx.x;
    const int tile = blk % NT;
    const int bc   = blk / NT;            // b*C + c
    const int c    = bc % C_;
    const long row = (long)bc * L_;
    const int  t0  = tile * TILE - HALO;  // global pos of buffer p=0

    float h0v[4], h1v[4];
#pragma unroll
    for (int k = 0; k < 4; ++k) { h0v[k] = h0[c*4+k]; h1v[k] = h1[c*4+k]; }
    float wv[10];
#pragma unroll
    for (int i = 0; i < 10; ++i) wv[i] = w[c*10+i];

    h8 lw[UMAX];     // running low residual (own units, registers)
    h8 yacc[UMAX];   // packed y accumulator

    const _Float16 w9h = (_Float16)wv[9];

    // Stage x as fp16 (zeros left of t=0); init lw = x, y = w9*x.
#pragma unroll
    for (int u = 0; u < UMAX; ++u) {
        yacc[u] = sp8((_Float16)0.f);
        const int un = tid + u * BLK;
        if (un < NU) {
            const int p = 8 * un;
            const int t = t0 + p;
            float4 xa = make_float4(0.f, 0.f, 0.f, 0.f);
            float4 xb = make_float4(0.f, 0.f, 0.f, 0.f);
            if (t >= 0) { xa = ld4f(&x[row + t]); xb = ld4f(&x[row + t + 4]); }
            const h8 hv = pack8(xa, xb);
            st8(&buf[0][p], hv);
            lw[u] = hv;
            if (un >= HALO_U) yacc[u] = sp8(w9h) * hv;
        }
    }
    __syncthreads();

    level_pass<1,   1,  false>(buf[0], buf[1], h0v, h1v, wv[8], 0.f, lw, yacc, tid); __syncthreads();
    level_pass<2,   2,  false>(buf[1], buf[0], h0v, h1v, wv[7], 0.f, lw, yacc, tid); __syncthreads();
    level_pass<4,   4,  false>(buf[0], buf[1], h0v, h1v, wv[6], 0.f, lw, yacc, tid); __syncthreads();
    level_pass<8,   7,  false>(buf[1], buf[0], h0v, h1v, wv[5], 0.f, lw, yacc, tid); __syncthreads();
    level_pass<16,  13, false>(buf[0], buf[1], h0v, h1v, wv[4], 0.f, lw, yacc, tid); __syncthreads();
    level_pass<32,  25, false>(buf[1], buf[0], h0v, h1v, wv[3], 0.f, lw, yacc, tid); __syncthreads();
    level_pass<64,  49, false>(buf[0], buf[1], h0v, h1v, wv[2], 0.f, lw, yacc, tid); __syncthreads();
    level_pass<128, 97, true >(buf[1], buf[0], h0v, h1v, wv[1], wv[0], lw, yacc, tid);

    // Epilogue: unpack to fp32, GELU, two float4 stores per unit.
#pragma unroll
    for (int u = 0; u < UMAX; ++u) {
        const int un = tid + u * BLK;
        if (un >= HALO_U && un < NU) {
            const int p = 8 * un;
            const h8 v = yacc[u];
            float4 oa, ob;
            oa.x = gelu_f((float)v[0]); oa.y = gelu_f((float)v[1]);
            oa.z = gelu_f((float)v[2]); oa.w = gelu_f((float)v[3]);
            ob.x = gelu_f((float)v[4]); ob.y = gelu_f((float)v[5]);
            ob.z = gelu_f((float)v[6]); ob.w = gelu_f((float)v[7]);
            st4f(&out[row + t0 + p], oa);
            st4f(&out[row + t0 + p + 4], ob);
        }
    }
}

}  // namespace

extern "C" void kernel_launch(void* const* d_in, const int* in_sizes, int n_in,
                              void* d_out, int out_size, void* d_ws, size_t ws_size,
                              hipStream_t stream)
{
    const float* x  = (const float*)d_in[0];
    const float* h0 = (const float*)d_in[1];
    const float* h1 = (const float*)d_in[2];
    const float* w  = (const float*)d_in[3];
    float* out = (float*)d_out;

    const int nblocks = (out_size / L_) * NT;   // B*C*NT = 8192 blocks of 128
    cmrc_kernel<<<nblocks, BLK, 0, stream>>>(x, h0, h1, w, out);
}

// Round 15
// 42.228 us; speedup vs baseline: 1.1580x; 1.1109x over previous
//
#include <hip/hip_runtime.h>
#include <cmath>

namespace {

typedef _Float16 h8 __attribute__((ext_vector_type(8)));
typedef _Float16 h2 __attribute__((ext_vector_type(2)));
typedef __fp16   fp2 __attribute__((ext_vector_type(2)));   // cvt_pkrtz native type

constexpr int C_     = 64;
constexpr int L_     = 32768;
constexpr int TILE   = 4096;
constexpr int HALO   = 776;           // receptive field 765, rounded to unit-8
constexpr int NB     = TILE + HALO;   // 4872 halfs
constexpr int NU     = NB / 8;        // 609 h8 units
constexpr int HALO_U = HALO / 8;      // 97
constexpr int NT     = L_ / TILE;     // 8 tiles per row
constexpr int BLK    = 256;
constexpr int S2N    = NU - 2 * BLK;  // 97: threads owning a third unit

__device__ __forceinline__ h8 ld8(const _Float16* p) { return *reinterpret_cast<const h8*>(p); }
__device__ __forceinline__ void st8(_Float16* p, h8 v) { *reinterpret_cast<h8*>(p) = v; }
__device__ __forceinline__ float4 ld4f(const float* p) { return *reinterpret_cast<const float4*>(p); }
__device__ __forceinline__ void st4f(float* p, float4 v) { *reinterpret_cast<float4*>(p) = v; }
__device__ __forceinline__ h8 sp8(_Float16 v) { return (h8){v,v,v,v,v,v,v,v}; }

// Guaranteed v_pk_fma_f16 (r10: measured win vs mul/add trees).
__device__ __forceinline__ h8 fma8(h8 a, h8 b, h8 c) {
    return __builtin_elementwise_fma(a, b, c);
}

template<int K>
__device__ __forceinline__ h8 shconc(h8 A, h8 B) {
    return __builtin_shufflevector(A, B, K, K+1, K+2, K+3, K+4, K+5, K+6, K+7);
}

// f32x8 -> fp16x8 via v_cvt_pkrtz_f16_f32; absmax-verified (r12/r14: 0.0078125).
__device__ __forceinline__ h2 pkrtz(float lo, float hi) {
    const fp2 r = __builtin_amdgcn_cvt_pkrtz(lo, hi);
    return __builtin_bit_cast(h2, r);
}
__device__ __forceinline__ h8 pack8(float4 a, float4 b) {
    const h2 p0 = pkrtz(a.x, a.y);
    const h2 p1 = pkrtz(a.z, a.w);
    const h2 p2 = pkrtz(b.x, b.y);
    const h2 p3 = pkrtz(b.z, b.w);
    return (h8){p0[0], p0[1], p1[0], p1[1], p2[0], p2[1], p3[0], p3[1]};
}

// tanh-form GELU: v * sigmoid(1.5958*v + 0.07135*v^3); absmax-verified vs erf
// across eight rounds (identical 0.0078125 overall absmax).
__device__ __forceinline__ float gelu_f(float v) {
    const float z = v * (1.5957691216057308f + 0.0713548162726f * v * v);
    const float e = __expf(-z);
    return v * __builtin_amdgcn_rcpf(1.0f + e);
}

// Tap gather + two 4-tap dots + in-place publish for one unit of one level.
template<int D, bool LAST>
__device__ __forceinline__ void unit_step(const _Float16* __restrict__ src,
                                          _Float16* __restrict__ dst, int un,
                                          h8& lwv, h8& yv, bool doY,
                                          const _Float16* c1, const _Float16* c0)
{
    const int p = 8 * un;
    const h8 T3 = lwv;
    h8 T0, T1, T2;
    if constexpr (D == 1) {
        const h8 Lv = ld8(&src[p - 8]);
        T0 = shconc<5>(Lv, T3); T1 = shconc<6>(Lv, T3); T2 = shconc<7>(Lv, T3);
    } else if constexpr (D == 2) {
        const h8 Lv = ld8(&src[p - 8]);
        T0 = shconc<2>(Lv, T3); T1 = shconc<4>(Lv, T3); T2 = shconc<6>(Lv, T3);
    } else if constexpr (D == 4) {
        const h8 Lv = ld8(&src[p - 8]);
        const h8 LL = ld8(&src[p - 16]);
        T0 = shconc<4>(LL, Lv); T1 = Lv; T2 = shconc<4>(Lv, T3);
    } else {
        T0 = ld8(&src[p - 3 * D]);
        T1 = ld8(&src[p - 2 * D]);
        T2 = ld8(&src[p - D]);
    }
    if (doY) {
        h8 yt = yv;
        yt = fma8(sp8(c1[0]), T0, yt);
        yt = fma8(sp8(c1[1]), T1, yt);
        yt = fma8(sp8(c1[2]), T2, yt);
        yt = fma8(sp8(c1[3]), T3, yt);
        yv = yt;
    }
    h8 nl = sp8(c0[0]) * T0;
    nl = fma8(sp8(c0[1]), T1, nl);
    nl = fma8(sp8(c0[2]), T2, nl);
    nl = fma8(sp8(c0[3]), T3, nl);
    if constexpr (LAST) {
        yv += nl;                      // c0 pre-folded with w0
    } else {
        lwv = nl;
        st8(&dst[p], nl);
    }
}

// One level, dilation D. Slots compile-time specialized and ordered so the
// UNCONDITIONAL slot1 issues its ds_reads first:
//  slot1 (un=tid+256 in [256,512)): no guard (>=97 always, <NU, y always).
//  slot2 (un=tid+512): exists iff tid<S2N=97; y always.
//  slot0 (un=tid): guard tid>=STARTU; y iff tid>=HALO_U.
// Coefficients: h0h/h1h/wh precomputed in fp16 once; per level only
// c1[t] = wih*h1h[t] (4 v_mul_f16) — c0 is level-invariant except LAST.
// Frontier recursion (correctness-proven r3..r14): STARTU per level
// 1,2,4,7,13,25,49,97; valid unit g at level D reads down to g-3D/8 >= prev
// STARTU, so below-frontier garbage is never read. Guards bound live ranges
// (r4-r7: unguarded variants -> 188 VGPR or scratch demotion).
template<int D, int STARTU, bool LAST>
__device__ __forceinline__ void level_pass(const _Float16* __restrict__ src,
                                           _Float16* __restrict__ dst,
                                           const _Float16* h0h, const _Float16* h1h,
                                           _Float16 wih, _Float16 w0h,
                                           h8* lw, h8* yacc, int tid)
{
    _Float16 c1[4], c0[4];
#pragma unroll
    for (int t = 0; t < 4; ++t) {
        c1[t] = wih * h1h[t];
        c0[t] = LAST ? (_Float16)(w0h * h0h[t]) : h0h[t];
    }
    unit_step<D, LAST>(src, dst, tid + BLK, lw[1], yacc[1], true, c1, c0);
    if (tid < S2N)
        unit_step<D, LAST>(src, dst, tid + 2 * BLK, lw[2], yacc[2], true, c1, c0);
    if (tid >= STARTU)
        unit_step<D, LAST>(src, dst, tid, lw[0], yacc[0], tid >= HALO_U, c1, c0);
}

// min-waves=8 (VGPR cap 64): this guarded structure measured 24 VGPR (r10) —
// 2.6x headroom. LDS 2x9744B -> 8 blocks/CU.
__global__ __launch_bounds__(BLK, 8)
void cmrc_kernel(const float* __restrict__ x,
                 const float* __restrict__ h0,
                 const float* __restrict__ h1,
                 const float* __restrict__ w,
                 float* __restrict__ out)
{
    __shared__ alignas(16) _Float16 buf[2][NB];

    const int tid  = threadIdx.x;
    const int blk  = blockIdx.x;
    const int tile = blk % NT;
    const int bc   = blk / NT;            // b*C + c
    const int c    = bc % C_;
    const long row = (long)bc * L_;
    const int  t0  = tile * TILE - HALO;  // global pos of buffer p=0

    // fp16 filter taps and level weights, converted ONCE.
    _Float16 h0h[4], h1h[4];
#pragma unroll
    for (int k = 0; k < 4; ++k) {
        h0h[k] = (_Float16)h0[c * 4 + k];
        h1h[k] = (_Float16)h1[c * 4 + k];
    }
    _Float16 wh[10];
#pragma unroll
    for (int i = 0; i < 10; ++i) wh[i] = (_Float16)w[c * 10 + i];

    h8 lw[3];     // running low residual (own units, registers)
    h8 yacc[3];   // packed y accumulator

    // Stage x as fp16 (zeros left of t=0); init lw = x, y = w9*x.
#pragma unroll
    for (int u = 0; u < 3; ++u) {
        yacc[u] = sp8((_Float16)0.f);
        const int un = tid + u * BLK;
        if (un < NU) {
            const int p = 8 * un;
            const int t = t0 + p;
            float4 xa = make_float4(0.f, 0.f, 0.f, 0.f);
            float4 xb = make_float4(0.f, 0.f, 0.f, 0.f);
            if (t >= 0) { xa = ld4f(&x[row + t]); xb = ld4f(&x[row + t + 4]); }
            const h8 hv = pack8(xa, xb);
            st8(&buf[0][p], hv);
            lw[u] = hv;
            if (un >= HALO_U) yacc[u] = sp8(wh[9]) * hv;
        }
    }
    __syncthreads();

    level_pass<1,   1,  false>(buf[0], buf[1], h0h, h1h, wh[8], (_Float16)0.f, lw, yacc, tid); __syncthreads();
    level_pass<2,   2,  false>(buf[1], buf[0], h0h, h1h, wh[7], (_Float16)0.f, lw, yacc, tid); __syncthreads();
    level_pass<4,   4,  false>(buf[0], buf[1], h0h, h1h, wh[6], (_Float16)0.f, lw, yacc, tid); __syncthreads();
    level_pass<8,   7,  false>(buf[1], buf[0], h0h, h1h, wh[5], (_Float16)0.f, lw, yacc, tid); __syncthreads();
    level_pass<16,  13, false>(buf[0], buf[1], h0h, h1h, wh[4], (_Float16)0.f, lw, yacc, tid); __syncthreads();
    level_pass<32,  25, false>(buf[1], buf[0], h0h, h1h, wh[3], (_Float16)0.f, lw, yacc, tid); __syncthreads();
    level_pass<64,  49, false>(buf[0], buf[1], h0h, h1h, wh[2], (_Float16)0.f, lw, yacc, tid); __syncthreads();
    level_pass<128, 97, true >(buf[1], buf[0], h0h, h1h, wh[1], wh[0],         lw, yacc, tid);

    // Epilogue: unpack to fp32, GELU, two float4 stores per unit.
#pragma unroll
    for (int u = 0; u < 3; ++u) {
        const int un = tid + u * BLK;
        if (un >= HALO_U && un < NU) {
            const int p = 8 * un;
            const h8 v = yacc[u];
            float4 oa, ob;
            oa.x = gelu_f((float)v[0]); oa.y = gelu_f((float)v[1]);
            oa.z = gelu_f((float)v[2]); oa.w = gelu_f((float)v[3]);
            ob.x = gelu_f((float)v[4]); ob.y = gelu_f((float)v[5]);
            ob.z = gelu_f((float)v[6]); ob.w = gelu_f((float)v[7]);
            st4f(&out[row + t0 + p], oa);
            st4f(&out[row + t0 + p + 4], ob);
        }
    }
}

}  // namespace

extern "C" void kernel_launch(void* const* d_in, const int* in_sizes, int n_in,
                              void* d_out, int out_size, void* d_ws, size_t ws_size,
                              hipStream_t stream)
{
    const float* x  = (const float*)d_in[0];
    const float* h0 = (const float*)d_in[1];
    const float* h1 = (const float*)d_in[2];
    const float* w  = (const float*)d_in[3];
    float* out = (float*)d_out;

    const int nblocks = (out_size / L_) * NT;   // B*C*NT = 4096
    cmrc_kernel<<<nblocks, BLK, 0, stream>>>(x, h0, h1, w, out);
}